// Round 3
// baseline (168.520 us; speedup 1.0000x reference)
//
#include <hip/hip_runtime.h>

typedef unsigned short u16;
typedef unsigned int u32;
typedef short bf16x8 __attribute__((ext_vector_type(8)));
typedef float f32x4 __attribute__((ext_vector_type(4)));
typedef u16 u16x4 __attribute__((ext_vector_type(4)));

#define NAG 32
#define STATE 512
#define EMBED 64
#define TB 64   // samples per block; 512 threads (8 waves); grid 512 = 2 blocks/CU

// d_ws bf16 layout (u16 element offsets).
#define OFF_W1L1 0
#define OFF_W2L1 32768
#define OFF_B1W  65536
#define OFF_B2L1 98304
#define OFF_W1L2 131072
#define OFF_W2L2 262144
#define WS_TOTAL 266240

// smem layout (u16 offsets). Total 31744 u16 = 62 KB -> 2 blocks/CU, 16 waves/CU.
#define Y_STR    200          // y[64][200]: [0,64) h1 | [64,128) h2 | [128,192) b1v->hidden
#define SB_OFF   12800        // sb[2][64][72] bf16 state K-slices
#define SB_STR   72
#define SB_BUF   (64 * 72)
#define W1BS_OFF 22016        // w1l2b bf16 [2048]
#define QST_OFF  24064        // qs^T bf16 [32][68]
#define QST_STR  68
#define PBUF_OFF 12800        // phase-B partials [4][64][72] — overlays sb/w1bs/qst (dead)
#define PBUF_STR 72
#define PBUF_WV  (64 * 72)
#define QACC_OFF  31232       // f32[64]
#define QACC2_OFF 31360       // f32[2][64]
#define B2WV_OFF  31616       // f32[64]
#define SMEM_U16  31744

__device__ __forceinline__ float bf2f(u16 u) {
    u32 i = ((u32)u) << 16; float f;
    __builtin_memcpy(&f, &i, 4); return f;
}
__device__ __forceinline__ u16 f2bf(float f) {
    u32 i; __builtin_memcpy(&i, &f, 4);
    return (u16)((i + 0x8000u) >> 16);
}
__device__ __forceinline__ bf16x8 ld8(const u16* p) {
    return *reinterpret_cast<const bf16x8*>(p);
}
__device__ __forceinline__ bf16x8 cvt8(f32x4 a, f32x4 b) {
    bf16x8 r;
#pragma unroll
    for (int i = 0; i < 4; ++i) r[i]     = (short)f2bf(a[i]);
#pragma unroll
    for (int i = 0; i < 4; ++i) r[i + 4] = (short)f2bf(b[i]);
    return r;
}

__global__ __launch_bounds__(256) void cvt_weights(
    const float* __restrict__ w1l1w, const float* __restrict__ w2l1w,
    const float* __restrict__ b1w,   const float* __restrict__ b2l1w,
    const float* __restrict__ w1l2w, const float* __restrict__ w2l2w,
    u16* __restrict__ ws)
{
    int idx = blockIdx.x * 256 + threadIdx.x;
    const float* src; int off;
    if      (idx < OFF_W2L1)  { src = w1l1w; off = OFF_W1L1; }
    else if (idx < OFF_B1W)   { src = w2l1w; off = OFF_W2L1; }
    else if (idx < OFF_B2L1)  { src = b1w;   off = OFF_B1W;  }
    else if (idx < OFF_W1L2)  { src = b2l1w; off = OFF_B2L1; }
    else if (idx < OFF_W2L2)  { src = w1l2w; off = OFF_W1L2; }
    else if (idx < WS_TOTAL)  { src = w2l2w; off = OFF_W2L2; }
    else return;
    ws[idx] = f2bf(src[idx - off]);
}

// 8-wave / 512-thread decomposition (TB=64 samples/block, 2 blocks/CU ->
// 4 waves/SIMD for latency hiding; VGPR held <=128 via launch_bounds):
//  Phase A: wave w owns 32 features [32w,32w+32) x all 64 samples; weights
//           direct-from-global (L2) with 1-slice reg prefetch; states staged
//           in LDS bf16 double-buffered (coalesced).
//           waves 6,7 (hb features) dot with b2l2w immediately -> qacc2[2].
//  Phase B: wave (ah=w&3, sh=w>>2) owns agents [8ah,8ah+8) x samples
//           [32sh,32sh+32); partial hidden in regs, pbuf[4] + one reduction.
//  Phase C: waves 0-3, 16 samples each: w2 = |h2 @ W2l2^T + b| dot hidden.
//  Phase D: out = qacc + qacc2[0] + qacc2[1] + b2l2b.
__global__ __launch_bounds__(512, 4) void qmix_kernel(
    const float* __restrict__ qs,    const float* __restrict__ st,
    const u16*  __restrict__ wsb,
    const float* __restrict__ w1l1b, const float* __restrict__ w1l2b,
    const float* __restrict__ w2l1b, const float* __restrict__ w2l2b,
    const float* __restrict__ b1b,   const float* __restrict__ b2l1b,
    const float* __restrict__ b2l2w, const float* __restrict__ b2l2b,
    float* __restrict__ out)
{
    __shared__ u16 smem[SMEM_U16];
    float* qaccF  = (float*)(smem + QACC_OFF);
    float* qacc2F = (float*)(smem + QACC2_OFF);   // [2][64]
    float* b2wvF  = (float*)(smem + B2WV_OFF);

    const int t    = threadIdx.x;
    const int wave = t >> 6, lane = t & 63;
    const int m = lane & 15, quad = lane >> 4;
    const int sbase = blockIdx.x * TB;

    // ---- prologue staging ----
    if (t < 64) b2wvF[t] = b2l2w[t];
    if (t < 256) {   // qs -> bf16 transposed [agent][sample]
        const float* qp = qs + (size_t)sbase * NAG + t * 8;
        f32x4 q0 = *reinterpret_cast<const f32x4*>(qp);
        f32x4 q1 = *reinterpret_cast<const f32x4*>(qp + 4);
        const int s = t >> 2, a0 = (t & 3) * 8;
#pragma unroll
        for (int j = 0; j < 4; ++j) smem[QST_OFF + (a0 + j) * QST_STR + s]     = f2bf(q0[j]);
#pragma unroll
        for (int j = 0; j < 4; ++j) smem[QST_OFF + (a0 + 4 + j) * QST_STR + s] = f2bf(q1[j]);
    } else {         // w1l2b -> bf16
        const int i = t & 255;
        f32x4 w0 = *reinterpret_cast<const f32x4*>(w1l2b + i * 8);
        f32x4 w1 = *reinterpret_cast<const f32x4*>(w1l2b + i * 8 + 4);
        *reinterpret_cast<bf16x8*>(&smem[W1BS_OFF + i * 8]) = cvt8(w0, w1);
    }

    // states staging: thread owns (sample t>>3, chunk t&7): one bf16x8/slice
    const int ss1 = t >> 3, c8 = t & 7;
    const float* stb = st + (size_t)sbase * STATE;
    {   // stage slice 0
        const float* g1 = stb + (size_t)ss1 * STATE + c8 * 8;
        f32x4 a0 = *reinterpret_cast<const f32x4*>(g1);
        f32x4 a1 = *reinterpret_cast<const f32x4*>(g1 + 4);
        *reinterpret_cast<bf16x8*>(&smem[SB_OFF + ss1 * SB_STR + c8 * 8]) = cvt8(a0, a1);
    }

    // ---- Phase A: wave w owns features [32w, 32w+32) ----
    const u16* wAw = wsb + (size_t)(wave * 32) * STATE;
    bf16x8 bfr[2][2][2];
#pragma unroll
    for (int ot = 0; ot < 2; ++ot) {
        const u16* wr = wAw + (size_t)(ot * 16 + m) * STATE + quad * 8;
        bfr[0][ot][0] = ld8(wr);
        bfr[0][ot][1] = ld8(wr + 32);
    }
    __syncthreads();   // sb[0] + prologue visible

    f32x4 acc[4][2] = {};
#pragma unroll
    for (int ks = 0; ks < 8; ++ks) {
        f32x4 sa0 = {}, sa1 = {};
        if (ks < 7) {
            const float* g1 = stb + (size_t)ss1 * STATE + (ks + 1) * 64 + c8 * 8;
            sa0 = *reinterpret_cast<const f32x4*>(g1);
            sa1 = *reinterpret_cast<const f32x4*>(g1 + 4);
#pragma unroll
            for (int ot = 0; ot < 2; ++ot) {
                const u16* wr = wAw + (size_t)(ot * 16 + m) * STATE + (ks + 1) * 64 + quad * 8;
                bfr[(ks + 1) & 1][ot][0] = ld8(wr);
                bfr[(ks + 1) & 1][ot][1] = ld8(wr + 32);
            }
        }
        const u16* sbc = smem + SB_OFF + (ks & 1) * SB_BUF;
#pragma unroll
        for (int st2 = 0; st2 < 4; ++st2) {
            const int row = st2 * 16 + m;
            bf16x8 af0 = ld8(&sbc[row * SB_STR + quad * 8]);
            bf16x8 af1 = ld8(&sbc[row * SB_STR + (quad + 4) * 8]);
#pragma unroll
            for (int ot = 0; ot < 2; ++ot)
                acc[st2][ot] = __builtin_amdgcn_mfma_f32_16x16x32_bf16(af0, bfr[ks & 1][ot][0], acc[st2][ot], 0, 0, 0);
#pragma unroll
            for (int ot = 0; ot < 2; ++ot)
                acc[st2][ot] = __builtin_amdgcn_mfma_f32_16x16x32_bf16(af1, bfr[ks & 1][ot][1], acc[st2][ot], 0, 0, 0);
        }
        if (ks < 7) {
            u16* dst = smem + SB_OFF + ((ks + 1) & 1) * SB_BUF;
            *reinterpret_cast<bf16x8*>(&dst[ss1 * SB_STR + c8 * 8]) = cvt8(sa0, sa1);
        }
        __syncthreads();
    }

    // ---- Phase A epilogue: grp = wave>>1 (0:h1, 1:h2, 2:b1v, 3:hb), half = wave&1 ----
    {
        const int grp = wave >> 1, half = wave & 1;
        if (grp < 3) {
            const float* barr = (grp == 0) ? w1l1b : (grp == 1) ? w2l1b : b1b;
            const bool isrelu = (grp != 2);
            float wb[2];
#pragma unroll
            for (int ot = 0; ot < 2; ++ot) wb[ot] = barr[half * 32 + ot * 16 + m];
#pragma unroll
            for (int st2 = 0; st2 < 4; ++st2)
#pragma unroll
                for (int ot = 0; ot < 2; ++ot)
#pragma unroll
                    for (int r = 0; r < 4; ++r) {
                        float v = acc[st2][ot][r] + wb[ot];
                        if (isrelu) v = fmaxf(v, 0.f);
                        smem[(st2 * 16 + quad * 4 + r) * Y_STR + grp * 64 + half * 32 + ot * 16 + m] = f2bf(v);
                    }
        } else {
            float wb[2], bw[2];
#pragma unroll
            for (int ot = 0; ot < 2; ++ot) wb[ot] = b2l1b[half * 32 + ot * 16 + m];
#pragma unroll
            for (int ot = 0; ot < 2; ++ot) bw[ot] = b2wvF[half * 32 + ot * 16 + m];
#pragma unroll
            for (int st2 = 0; st2 < 4; ++st2)
#pragma unroll
                for (int r = 0; r < 4; ++r) {
                    float pd = 0.f;
#pragma unroll
                    for (int ot = 0; ot < 2; ++ot)
                        pd += fmaxf(acc[st2][ot][r] + wb[ot], 0.f) * bw[ot];
#pragma unroll
                    for (int off = 1; off < 16; off <<= 1) pd += __shfl_xor(pd, off, 64);
                    if (m == 0) qacc2F[half * 64 + st2 * 16 + quad * 4 + r] = pd;
                }
        }
    }
    __syncthreads();   // y + qacc2 ready

    // ---- Phase B: wave (ah, sh): agents [8ah,8ah+8) x samples [32sh,32sh+32) ----
    const int ah = wave & 3, sh = wave >> 2;
    bf16x8 h1f[2][2];
#pragma unroll
    for (int st2 = 0; st2 < 2; ++st2) {
        const int row = sh * 32 + st2 * 16 + m;
        h1f[st2][0] = ld8(&smem[row * Y_STR + quad * 8]);
        h1f[st2][1] = ld8(&smem[row * Y_STR + 32 + quad * 8]);
    }

    const u16* wB = wsb + OFF_W1L2 + (size_t)(ah * 8) * 64 * EMBED;
    f32x4 hacc[2][4] = {};
#pragma unroll
    for (int ag = 0; ag < 8; ++ag) {
        const int a = ah * 8 + ag;
        bf16x8 bb[4][2];
#pragma unroll
        for (int ot = 0; ot < 4; ++ot) {
            const u16* wr = wB + (size_t)(ag * 64 + ot * 16 + m) * EMBED + quad * 8;
            bb[ot][0] = ld8(wr);
            bb[ot][1] = ld8(wr + 32);
        }
        float bias[4];
#pragma unroll
        for (int ot = 0; ot < 4; ++ot) bias[ot] = bf2f(smem[W1BS_OFF + a * EMBED + ot * 16 + m]);
#pragma unroll
        for (int st2 = 0; st2 < 2; ++st2) {
            u16x4 qv = *reinterpret_cast<const u16x4*>(
                &smem[QST_OFF + a * QST_STR + sh * 32 + st2 * 16 + quad * 4]);
#pragma unroll
            for (int ot = 0; ot < 4; ++ot) {
                f32x4 p = {};
                p = __builtin_amdgcn_mfma_f32_16x16x32_bf16(h1f[st2][0], bb[ot][0], p, 0, 0, 0);
                p = __builtin_amdgcn_mfma_f32_16x16x32_bf16(h1f[st2][1], bb[ot][1], p, 0, 0, 0);
#pragma unroll
                for (int r = 0; r < 4; ++r)
                    hacc[st2][ot][r] += bf2f((u16)qv[r]) * fabsf(p[r] + bias[ot]);
            }
        }
    }
    __syncthreads();   // all waves done with w1bs/qst/sb -> safe to overlay pbuf

#pragma unroll
    for (int st2 = 0; st2 < 2; ++st2)
#pragma unroll
        for (int ot = 0; ot < 4; ++ot)
#pragma unroll
            for (int r = 0; r < 4; ++r)
                smem[PBUF_OFF + ah * PBUF_WV
                     + (sh * 32 + st2 * 16 + quad * 4 + r) * PBUF_STR + ot * 16 + m]
                    = f2bf(hacc[st2][ot][r]);
    __syncthreads();   // partials in

    // ---- reduction: hidden = elu(sum_ah pbuf + b1v), in place over b1v ----
    {
        const int s  = t >> 3;             // 0..63
        const int eb = (t & 7) * 8;        // 0..56
        float v[8];
#pragma unroll
        for (int j = 0; j < 8; ++j) v[j] = 0.f;
#pragma unroll
        for (int pw = 0; pw < 4; ++pw) {
            u16x4 x0 = *reinterpret_cast<const u16x4*>(
                &smem[PBUF_OFF + pw * PBUF_WV + s * PBUF_STR + eb]);
            u16x4 x1 = *reinterpret_cast<const u16x4*>(
                &smem[PBUF_OFF + pw * PBUF_WV + s * PBUF_STR + eb + 4]);
#pragma unroll
            for (int j = 0; j < 4; ++j) v[j]     += bf2f((u16)x0[j]);
#pragma unroll
            for (int j = 0; j < 4; ++j) v[4 + j] += bf2f((u16)x1[j]);
        }
        bf16x8 bv = ld8(&smem[s * Y_STR + 128 + eb]);
        bf16x8 o;
#pragma unroll
        for (int j = 0; j < 8; ++j) {
            float h = v[j] + bf2f((u16)bv[j]);
            h = (h > 0.f) ? h : (__expf(h) - 1.f);
            o[j] = (short)f2bf(h);
        }
        *reinterpret_cast<bf16x8*>(&smem[s * Y_STR + 128 + eb]) = o;
    }
    __syncthreads();   // hidden ready

    // ---- Phase C (waves 0-3): w2 = |h2 @ W2l2^T + b|; q = sum_e hidden*w2 ----
    if (wave < 4) {
        const int s0 = wave * 16;
        bf16x8 h2f0 = ld8(&smem[(s0 + m) * Y_STR + 64 + quad * 8]);
        bf16x8 h2f1 = ld8(&smem[(s0 + m) * Y_STR + 96 + quad * 8]);

        f32x4 qp = {};
#pragma unroll
        for (int tp = 0; tp < 4; ++tp) {
            const u16* wc = wsb + OFF_W2L2 + (size_t)(tp * 16 + m) * EMBED + quad * 8;
            bf16x8 c0 = ld8(wc);
            bf16x8 c1 = ld8(wc + 32);
            f32x4 p = {};
            p = __builtin_amdgcn_mfma_f32_16x16x32_bf16(h2f0, c0, p, 0, 0, 0);
            p = __builtin_amdgcn_mfma_f32_16x16x32_bf16(h2f1, c1, p, 0, 0, 0);
            const float bias = w2l2b[tp * 16 + m];
#pragma unroll
            for (int r = 0; r < 4; ++r)
                qp[r] += bf2f(smem[(s0 + quad * 4 + r) * Y_STR + 128 + tp * 16 + m]) * fabsf(p[r] + bias);
        }
#pragma unroll
        for (int off = 1; off < 16; off <<= 1) {
#pragma unroll
            for (int r = 0; r < 4; ++r) qp[r] += __shfl_xor(qp[r], off, 64);
        }
        if (m == 0) {
#pragma unroll
            for (int r = 0; r < 4; ++r) qaccF[s0 + quad * 4 + r] = qp[r];
        }
    }
    __syncthreads();   // qacc ready

    // ---- Phase D ----
    if (t < TB) out[sbase + t] = qaccF[t] + qacc2F[t] + qacc2F[64 + t] + b2l2b[0];
}

extern "C" void kernel_launch(void* const* d_in, const int* in_sizes, int n_in,
                              void* d_out, int out_size, void* d_ws, size_t ws_size,
                              hipStream_t stream)
{
    const float* qs    = (const float*)d_in[0];
    const float* st    = (const float*)d_in[1];
    const float* w1l1w = (const float*)d_in[2];
    const float* w1l1b = (const float*)d_in[3];
    const float* w1l2w = (const float*)d_in[4];
    const float* w1l2b = (const float*)d_in[5];
    const float* w2l1w = (const float*)d_in[6];
    const float* w2l1b = (const float*)d_in[7];
    const float* w2l2w = (const float*)d_in[8];
    const float* w2l2b = (const float*)d_in[9];
    const float* b1w   = (const float*)d_in[10];
    const float* b1b   = (const float*)d_in[11];
    const float* b2l1w = (const float*)d_in[12];
    const float* b2l1b = (const float*)d_in[13];
    const float* b2l2w = (const float*)d_in[14];
    const float* b2l2b = (const float*)d_in[15];

    u16* wsb = (u16*)d_ws;

    cvt_weights<<<(WS_TOTAL + 255) / 256, 256, 0, stream>>>(
        w1l1w, w2l1w, b1w, b2l1w, w1l2w, w2l2w, wsb);

    int B = in_sizes[0] / NAG;        // 32768
    int grid = B / TB;                // 512 blocks x 512 threads, 2 blocks/CU
    qmix_kernel<<<grid, 512, 0, stream>>>(
        qs, st, wsb,
        w1l1b, w1l2b, w2l1b, w2l2b, b1b, b2l1b, b2l2w, b2l2b,
        (float*)d_out);
}